// Round 11
// baseline (255.475 us; speedup 1.0000x reference)
//
#include <hip/hip_runtime.h>
#include <hip/hip_bf16.h>

// Problem constants
#define B_SZ   4096
#define OBS_N  128
#define HID    512
// tanh(x) = 1 - 2/(2^(x*2log2e)+1). We pre-scale all tanh-feeding weights and
// biases by TANH_SCALE at prep time so the fused epilogue needs no per-element
// v_mul, and the bias is folded into the MFMA accumulator init (no v_add).
#define TANH_SCALE 2.885390081777927f   // 2*log2(e)

// S-MAJOR q rows: r = s*4096 + b. Fused kernel: block = 64 rows (one s, 64 b's),
// 512 threads (8 waves), 3 hidden layers chained through a 64KB LDS buffer
// (XOR-swizzled chunks). Layers compute D = W·hs (out x batch).
// R21: phase-0 register peak was forcing KERNEL-WIDE spill (R20: WRITE 42MB
// = ~8 dwords/thread over the 128-VGPR wall; VGPR alloc is kernel-max).
// Phase 0 now uses a SINGLE weight slot wv[4] (refill after each kc) —
// legal relaxation of the distance-2 rule because the 20KB W0 table is
// L2-resident (shared by all 2112 blocks) and phase0 is only 80/600 of
// per-wave MFMA. Live peak drops ~136 -> ~112. Layers 1/2 keep the R18
// distance-2 + paired-ac zero-spill shape. obs tile staged to XOR-swizzled
// obs_t via global_load_lds with pre-swizzled source (both-sides rule).
// LDS 80KB/block = 2 blocks/CU. 2 dispatches: prep | fused.
// Distance-3 spills (R16) — never. L3 head split across all 8 waves.

typedef __bf16 bf16x8_t __attribute__((ext_vector_type(8)));
typedef float  f32x4_t  __attribute__((ext_vector_type(4)));

// input already scaled by TANH_SCALE (weights/bias pre-scaled at prep)
__device__ inline float fast_tanh_pre(float x) {
    float e = __builtin_amdgcn_exp2f(x);
    return fmaf(-2.f, __builtin_amdgcn_rcpf(e + 1.f), 1.f);
}

__device__ inline void gld_lds16(const void* g, void* l) {
    __builtin_amdgcn_global_load_lds(
        (const __attribute__((address_space(1))) void*)g,
        (__attribute__((address_space(3))) void*)l, 16, 0, 0);
}

// hs element (row, col): chunk c = col/8, phys = (c&~7)|((c^(row&7))&7),
// offset row*512 + phys*8 + col%8.
__device__ inline int hs_off(int row, int col) {
    int c = col >> 3;
    int phys = (c & ~7) | ((c ^ (row & 7)) & 7);
    return row * 512 + phys * 8 + (col & 7);
}

// ---------------- combined prep ----------------
// Grid layout (10504 blocks):
//   [0,512)        obs -> bf16 (float4)
//   [512,5632)     w1t/w2t/w3t/vw1t/vw2t MFMA tiling (5 x 1024)
//   [5632,9728)    acts_bf table
//   [9728,10368)   w0ta + vw0ta augmented K=160 tiled (320 each)
//   [10368,10376)  bias_s (scaled fp32 biases)
//   [10376,10504)  nbias = 0 (float4)
__global__ __launch_bounds__(256) void prep_kernel(
    const float* __restrict__ obs, const int* __restrict__ category,
    const float* __restrict__ qw0, const float* __restrict__ qb0,
    const float* __restrict__ qw1, const float* __restrict__ qw2,
    const float* __restrict__ qw3,
    const float* __restrict__ vw0, const float* __restrict__ vb0,
    const float* __restrict__ vw1, const float* __restrict__ vw2,
    const float* __restrict__ qb1, const float* __restrict__ qb2,
    const float* __restrict__ vb1, const float* __restrict__ vb2,
    __hip_bfloat16* __restrict__ obs_bf,
    __hip_bfloat16* __restrict__ w1t, __hip_bfloat16* __restrict__ w2t,
    __hip_bfloat16* __restrict__ w3t,
    __hip_bfloat16* __restrict__ vw1t, __hip_bfloat16* __restrict__ vw2t,
    __hip_bfloat16* __restrict__ w0ta, __hip_bfloat16* __restrict__ vw0ta,
    __hip_bfloat16* __restrict__ acts_bf, float* __restrict__ bias_s,
    float* __restrict__ nbias)
{
    const int bid = blockIdx.x, tid = threadIdx.x;
    if (bid < 512) {           // obs -> bf16, 4 elems/thread (float4)
        int i = bid * 1024 + tid * 4;
        float4 v = *(const float4*)&obs[i];
        union { __hip_bfloat16 b[4]; uint2 u; } o;
        o.b[0] = __float2bfloat16(v.x);
        o.b[1] = __float2bfloat16(v.y);
        o.b[2] = __float2bfloat16(v.z);
        o.b[3] = __float2bfloat16(v.w);
        *(uint2*)&obs_bf[i] = o.u;
    } else if (bid < 5632) {   // (512,512) -> MFMA-tiled
        int job = (bid - 512) >> 10;             // 0..4
        const float* srcs[5] = {qw1, qw2, qw3, vw1, vw2};
        __hip_bfloat16* dsts[5] = {w1t, w2t, w3t, vw1t, vw2t};
        // qw1/qw2/vw1/vw2 feed tanh -> pre-scale; qw3 (job 2) is the raw head
        float sc = (job == 2) ? 1.0f : TANH_SCALE;
        int idx = ((bid - 512) & 1023) * 256 + tid;    // 0..262143
        int e    = idx & 7;
        int lane = (idx >> 3) & 63;
        int tile, kc;
        if (job == 2) {        // w3t keeps the old tile-major layout (L3 path)
            kc   = (idx >> 9) & 15;
            tile = idx >> 13;
        } else {               // kc-major: one kc's 4 j-frags contiguous (4KB)
            int jj = (idx >> 9) & 3;
            kc     = (idx >> 11) & 15;
            int g  = idx >> 15;
            tile = g * 4 + jj;
        }
        int k = kc * 32 + (lane >> 4) * 8 + e;
        int n = tile * 16 + (lane & 15);
        dsts[job][idx] = __float2bfloat16(srcs[job][k * 512 + n] * sc);
    } else if (bid < 9728) {   // acts_bf table, s-major bf16: acts_bf[(s*4096+b)*8+d]
        int t = (bid - 5632) * 256 + tid;
        int d = t & 7;
        int r = t >> 3;
        int b = r & 4095, s = r >> 12;
        int U = (s >> 3) + ((d < (s & 7)) ? 1 : 0);
        float a = 0.f;
        if (U > 0) {
            float w = 0.125f, cum = 0.f;
            for (int j = 0; j < U; ++j) {
                cum += (float)category[b * 32 + j * 8 + d] * w;
                if (j == U - 1) a = -1.f + cum + 0.5f * w;
                w *= 0.0625f;
            }
        }
        acts_bf[t] = __float2bfloat16(a);
    } else if (bid < 10368) {  // w0ta + vw0ta: augmented K=160, kc-major tiled
        int sub = bid - 9728;            // 0..639
        bool isv = sub >= 320;
        int idx = (isv ? sub - 320 : sub) * 256 + tid;   // 0..81919
        int e    = idx & 7;
        int lane = (idx >> 3) & 63;
        int j    = (idx >> 9) & 3;
        int kcw  = idx >> 11;            // 0..159 = w*5 + kc
        int k = (kcw % 5) * 32 + (lane >> 4) * 8 + e;    // 0..159
        int n = ((kcw / 5) * 4 + j) * 16 + (lane & 15);  // 0..511
        float v = 0.f;
        if (!isv) {
            if (k < 136) v = qw0[k * 512 + n];           // obs + acts rows
            else if (k == 136) v = qb0[n];               // bias row
            w0ta[idx] = __float2bfloat16(v * TANH_SCALE);
        } else {
            if (k < 128) v = vw0[k * 512 + n];           // obs rows only
            else if (k == 136) v = vb0[n];
            vw0ta[idx] = __float2bfloat16(v * TANH_SCALE);
        }
    } else if (bid < 10376) {  // scaled fp32 biases for layers 1/2: qb1|qb2|vb1|vb2
        int idx = (bid - 10368) * 256 + tid;    // 0..2047
        const float* srcs[4] = {qb1, qb2, vb1, vb2};
        bias_s[idx] = srcs[idx >> 9][idx & 511] * TANH_SCALE;
    } else {                   // nbias = 0, 4 elems/thread (float4)
        int i = (bid - 10376) * 1024 + tid * 4;
        float4 z = {0.f, 0.f, 0.f, 0.f};
        *(float4*)&nbias[i] = z;
    }
}

// ---------------- epilogue: tanh(acc) -> hs (XOR-swizzled) ----------------
// acc is pre-scaled by TANH_SCALE and already includes the bias (acc init /
// bias row of the augmented W0).
__device__ inline void epi_store(
    __hip_bfloat16* hs, f32x4_t acc[4][4],
    int n0w, int quad, int t)
{
    #pragma unroll
    for (int j = 0; j < 4; ++j) {
        const int oc0 = n0w + j * 16 + quad * 4;     // 4 consecutive out cols
        const int cbase = oc0 >> 3;
        const int sub = (quad & 1) * 4;
        #pragma unroll
        for (int rt = 0; rt < 4; ++rt) {
            const int row = rt * 16 + t;
            union { __hip_bfloat16 b[4]; uint2 v; } o;
            o.b[0] = __float2bfloat16(fast_tanh_pre(acc[rt][j][0]));
            o.b[1] = __float2bfloat16(fast_tanh_pre(acc[rt][j][1]));
            o.b[2] = __float2bfloat16(fast_tanh_pre(acc[rt][j][2]));
            o.b[3] = __float2bfloat16(fast_tanh_pre(acc[rt][j][3]));
            const int phys = (cbase & ~7) | ((cbase ^ (row & 7)) & 7);
            *(uint2*)&hs[row * 512 + phys * 8 + sub] = o.v;
        }
    }
}

// ---------------- fused MLP layer: hs(64x512) = tanh(hs @ W^T + bias) ----------------
// Distance-2 weight prefetch (kc-pair loop, slots wA/wB) + PAIRED ac loads
// (a0/a1 -> 8 MFMAs -> a2/a3 -> 8 MFMAs) — R18-verified zero-spill config.
// Distance-3 spills (R16: WRITE 428MB) — do NOT add a third slot.
// bias_s is PRE-SCALED fp32 bias, folded into acc init (MFMA C-in).
__device__ inline void mfma_layer(
    __hip_bfloat16* hs, const __hip_bfloat16* __restrict__ Wt,
    const float* __restrict__ bias_s, int w, int lane)
{
    const int quad = lane >> 4, t = lane & 15;
    const int n0w = w * 64;
    // kc-major weight tiling: wave w's block = 32768 elems; per kc the 4
    // j-frags sit at consecutive 1KB offsets.
    const __hip_bfloat16* Wl = Wt + (size_t)w * 32768 + (size_t)lane * 8;
    f32x4_t acc[4][4];   // [rt = batch tile][j = out tile]
    #pragma unroll
    for (int j = 0; j < 4; ++j) {
        const f32x4_t bv = *(const f32x4_t*)&bias_s[n0w + j * 16 + quad * 4];
        #pragma unroll
        for (int rt = 0; rt < 4; ++rt)
            acc[rt][j] = bv;
    }
    bf16x8_t wA[4], wB[4];
    #pragma unroll
    for (int j = 0; j < 4; ++j) {
        wA[j] = *(const bf16x8_t*)(Wl + (size_t)(0 * 4 + j) * 512);
        wB[j] = *(const bf16x8_t*)(Wl + (size_t)(1 * 4 + j) * 512);
    }

    for (int m = 0; m < 8; ++m) {          // kc = 2m (slot A), 2m+1 (slot B)
        {   // even kc
            const int kc = 2 * m;
            const int craw = kc * 4 + quad;
            const int phys = (craw & ~7) | ((craw ^ (t & 7)) & 7);
            const __hip_bfloat16* hrow = &hs[t * 512 + phys * 8];
            bf16x8_t a0 = *(const bf16x8_t*)(hrow);
            bf16x8_t a1 = *(const bf16x8_t*)(hrow + 8192);
            __builtin_amdgcn_s_setprio(1);
            #pragma unroll
            for (int j = 0; j < 4; ++j) {
                acc[0][j] = __builtin_amdgcn_mfma_f32_16x16x32_bf16(wA[j], a0, acc[0][j], 0, 0, 0);
                acc[1][j] = __builtin_amdgcn_mfma_f32_16x16x32_bf16(wA[j], a1, acc[1][j], 0, 0, 0);
            }
            bf16x8_t a2 = *(const bf16x8_t*)(hrow + 2 * 8192);
            bf16x8_t a3 = *(const bf16x8_t*)(hrow + 3 * 8192);
            #pragma unroll
            for (int j = 0; j < 4; ++j) {
                acc[2][j] = __builtin_amdgcn_mfma_f32_16x16x32_bf16(wA[j], a2, acc[2][j], 0, 0, 0);
                acc[3][j] = __builtin_amdgcn_mfma_f32_16x16x32_bf16(wA[j], a3, acc[3][j], 0, 0, 0);
            }
            __builtin_amdgcn_s_setprio(0);
            if (m < 7) {
                #pragma unroll
                for (int j = 0; j < 4; ++j)
                    wA[j] = *(const bf16x8_t*)(Wl + (size_t)((kc + 2) * 4 + j) * 512);
            }
        }
        {   // odd kc
            const int kc = 2 * m + 1;
            const int craw = kc * 4 + quad;
            const int phys = (craw & ~7) | ((craw ^ (t & 7)) & 7);
            const __hip_bfloat16* hrow = &hs[t * 512 + phys * 8];
            bf16x8_t a0 = *(const bf16x8_t*)(hrow);
            bf16x8_t a1 = *(const bf16x8_t*)(hrow + 8192);
            __builtin_amdgcn_s_setprio(1);
            #pragma unroll
            for (int j = 0; j < 4; ++j) {
                acc[0][j] = __builtin_amdgcn_mfma_f32_16x16x32_bf16(wB[j], a0, acc[0][j], 0, 0, 0);
                acc[1][j] = __builtin_amdgcn_mfma_f32_16x16x32_bf16(wB[j], a1, acc[1][j], 0, 0, 0);
            }
            bf16x8_t a2 = *(const bf16x8_t*)(hrow + 2 * 8192);
            bf16x8_t a3 = *(const bf16x8_t*)(hrow + 3 * 8192);
            #pragma unroll
            for (int j = 0; j < 4; ++j) {
                acc[2][j] = __builtin_amdgcn_mfma_f32_16x16x32_bf16(wB[j], a2, acc[2][j], 0, 0, 0);
                acc[3][j] = __builtin_amdgcn_mfma_f32_16x16x32_bf16(wB[j], a3, acc[3][j], 0, 0, 0);
            }
            __builtin_amdgcn_s_setprio(0);
            if (m < 7) {
                #pragma unroll
                for (int j = 0; j < 4; ++j)
                    wB[j] = *(const bf16x8_t*)(Wl + (size_t)((kc + 2) * 4 + j) * 512);
            }
        }
    }
    __syncthreads();   // all reads of hs complete
    epi_store(hs, acc, n0w, quad, t);
    __syncthreads();   // hs now holds the layer output
}

// ---------------- fused MLP kernel: q-blocks [0,2048), v-blocks [2048,2112) ----------------
__global__ __launch_bounds__(512, 4) void fused_kernel(
    const __hip_bfloat16* __restrict__ obs_bf, // (4096,128) bf16 row-major
    const __hip_bfloat16* __restrict__ acts_bf,// (131072,8) bf16 s-major
    const __hip_bfloat16* __restrict__ w0ta,   // aug K=160 tiled, pre-scaled
    const __hip_bfloat16* __restrict__ vw0ta,
    const __hip_bfloat16* __restrict__ w1t, const float* __restrict__ qb1s,
    const __hip_bfloat16* __restrict__ w2t, const float* __restrict__ qb2s,
    const __hip_bfloat16* __restrict__ w3t, const float* __restrict__ qb3,
    float* __restrict__ advout,
    const __hip_bfloat16* __restrict__ vw1t, const float* __restrict__ vb1s,
    const __hip_bfloat16* __restrict__ vw2t, const float* __restrict__ vb2s,
    const float* __restrict__ vw3, const float* __restrict__ vb3,
    float* __restrict__ vout)
{
    __shared__ __hip_bfloat16 hs[64 * 512];     // 64 KB
    __shared__ __hip_bfloat16 obs_t[64 * 128];  // 16 KB XOR-swizzled obs tile
    const int bid = blockIdx.x;
    const int tid = threadIdx.x;
    const int w = tid >> 6, lane = tid & 63;
    const int quad = lane >> 4, t = lane & 15;
    const bool is_q = bid < 2048;
    const int s  = is_q ? (bid >> 6) : 0;
    const int mb = is_q ? (bid & 63) : (bid - 2048);
    const int n0w = w * 64;

    // ---- stage obs tile -> obs_t (swizzled): linear LDS dest, pre-swizzled
    //      global source (both-sides-or-neither). Wave w stages rows
    //      w*4..w*4+3 and w*4+32..35; (r+32)&7 == r&7 so same source chunk.
    {
        const int r0 = w * 4 + (lane >> 4);          // 0..31
        const int ph = lane & 15;                    // phys chunk in LDS
        const int c  = (ph & ~7) | ((ph ^ (r0 & 7)) & 7);   // logical chunk
        const __hip_bfloat16* g0 = obs_bf + ((size_t)(mb * 64 + r0)) * 128 + c * 8;
        gld_lds16(g0, &obs_t[(size_t)w * 512]);
        gld_lds16(g0 + 32 * 128, &obs_t[(size_t)(w * 4 + 32) * 128]);
    }
    __syncthreads();

    // ---- phase 0: D = W0a·[obs;acts;1] — 5-kc MFMA, B-frags from obs_t ----
    // SINGLE weight slot (wv): W0 table is 20KB, L2-resident across all
    // blocks; keeping one slot holds phase-0's live peak under the 128-VGPR
    // wall so the WHOLE kernel stays spill-free (R20 post-mortem).
    {
        const __hip_bfloat16* W0 = is_q ? w0ta : vw0ta;
        // per-wave aug weight block: 5 kc x 4 j x 512
        const __hip_bfloat16* Wl = W0 + (size_t)w * 10240 + (size_t)lane * 8;
        f32x4_t acc[4][4] = {};   // bias rides the k=136 weight row
        bf16x8_t wv[4];
        #pragma unroll
        for (int j = 0; j < 4; ++j)
            wv[j] = *(const bf16x8_t*)(Wl + (size_t)j * 512);
        // kc 0..3: obs part, paired a-loads; refill wv after each kc
        #pragma unroll
        for (int kc = 0; kc < 4; ++kc) {
            const int craw = kc * 4 + quad;
            const int phys = (craw & ~7) | ((craw ^ (t & 7)) & 7);
            const __hip_bfloat16* orow = &obs_t[t * 128 + phys * 8];
            bf16x8_t a0 = *(const bf16x8_t*)(orow);
            bf16x8_t a1 = *(const bf16x8_t*)(orow + 2048);
            __builtin_amdgcn_s_setprio(1);
            #pragma unroll
            for (int j = 0; j < 4; ++j) {
                acc[0][j] = __builtin_amdgcn_mfma_f32_16x16x32_bf16(wv[j], a0, acc[0][j], 0, 0, 0);
                acc[1][j] = __builtin_amdgcn_mfma_f32_16x16x32_bf16(wv[j], a1, acc[1][j], 0, 0, 0);
            }
            bf16x8_t a2 = *(const bf16x8_t*)(orow + 2 * 2048);
            bf16x8_t a3 = *(const bf16x8_t*)(orow + 3 * 2048);
            #pragma unroll
            for (int j = 0; j < 4; ++j) {
                acc[2][j] = __builtin_amdgcn_mfma_f32_16x16x32_bf16(wv[j], a2, acc[2][j], 0, 0, 0);
                acc[3][j] = __builtin_amdgcn_mfma_f32_16x16x32_bf16(wv[j], a3, acc[3][j], 0, 0, 0);
            }
            __builtin_amdgcn_s_setprio(0);
            #pragma unroll
            for (int j = 0; j < 4; ++j)   // refill for kc+1 (obs or aug)
                wv[j] = *(const bf16x8_t*)(Wl + (size_t)((kc + 1) * 4 + j) * 512);
        }
        // kc 4: aug part (acts + 1.0 + bias row); wv holds kc4
        {
            bf16x8_t bfrag[4];
            #pragma unroll
            for (int rt = 0; rt < 4; ++rt) {
                union { bf16x8_t vec; unsigned short u[8]; } bu;
                #pragma unroll
                for (int i = 0; i < 8; ++i) bu.u[i] = 0;
                if (quad == 1) bu.u[0] = 0x3F80;   // bf16 1.0 (k=136)
                if (is_q && quad == 0) {           // k=128..135 = acts
                    const long r = (long)s * 4096 + mb * 64 + rt * 16 + t;
                    bu.vec = *(const bf16x8_t*)&acts_bf[r * 8];
                }
                bfrag[rt] = bu.vec;
            }
            __builtin_amdgcn_s_setprio(1);
            #pragma unroll
            for (int j = 0; j < 4; ++j)
                #pragma unroll
                for (int rt = 0; rt < 4; ++rt)
                    acc[rt][j] = __builtin_amdgcn_mfma_f32_16x16x32_bf16(wv[j], bfrag[rt], acc[rt][j], 0, 0, 0);
            __builtin_amdgcn_s_setprio(0);
        }
        epi_store(hs, acc, n0w, quad, t);
    }
    __syncthreads();

    // ---- layers 1 and 2 ----
    mfma_layer(hs, is_q ? w1t : vw1t, is_q ? qb1s : vb1s, w, lane);
    mfma_layer(hs, is_q ? w2t : vw2t, is_q ? qb2s : vb2s, w, lane);

    // ---- layer 3 ----
    if (is_q) {
        // diag slice: 64 rows x 16 cols. ALL 8 waves: w&3 picks the row group,
        // w>>2 picks the kc half (0-7 / 8-15); partials in two LDS slabs.
        f32x4_t acc = {};
        {
            const __hip_bfloat16* W3l = w3t + ((size_t)s * 16 * 64 + (size_t)lane) * 8;
            const int kc0 = (w >> 2) * 8;
            const int wrow = (w & 3) * 16 + t;
            #pragma unroll
            for (int kk = 0; kk < 8; ++kk) {
                const int kc = kc0 + kk;
                const int craw = kc * 4 + quad;
                const int phys = (craw & ~7) | ((craw ^ (t & 7)) & 7);
                bf16x8_t a = *(const bf16x8_t*)&hs[wrow * 512 + phys * 8];
                bf16x8_t bq = *(const bf16x8_t*)(W3l + (size_t)kc * 512);
                acc = __builtin_amdgcn_mfma_f32_16x16x32_bf16(a, bq, acc, 0, 0, 0);
            }
        }
        __syncthreads();   // L3 reads of hs done; hs reusable as fp32 staging
        float* hsf = (float*)hs;   // two 64x16 fp32 slabs: [0..1023] and [1024..2047]
        {
            const float add = (w < 4) ? qb3[s * 16 + t] : 0.f;   // bias once
            const int base = (w >> 2) * 1024;
            #pragma unroll
            for (int rr = 0; rr < 4; ++rr)
                hsf[base + ((w & 3) * 16 + quad * 4 + rr) * 16 + t] = acc[rr] + add;
        }
        __syncthreads();
        // coalesced store: thread -> (row = tid>>3, colpair = tid&7), 64B/row
        const int row = tid >> 3, cp = tid & 7;
        float2 lo = *(const float2*)&hsf[row * 16 + cp * 2];
        float2 hi = *(const float2*)&hsf[1024 + row * 16 + cp * 2];
        float2 v2 = {lo.x + hi.x, lo.y + hi.y};
        *(float2*)&advout[(size_t)(mb * 64 + row) * 512 + s * 16 + cp * 2] = v2;
    } else {
        // value head: row = tid>>3 (0..63), seg = tid&7 sums 64 elems
        const int row = tid >> 3, seg = tid & 7;
        float sum = 0.f;
        for (int k = seg * 64; k < seg * 64 + 64; ++k)
            sum += __bfloat162float(hs[hs_off(row, k)]) * vw3[k];
        sum += __shfl_xor(sum, 1);
        sum += __shfl_xor(sum, 2);
        sum += __shfl_xor(sum, 4);
        if (seg == 0) vout[mb * 64 + row] = sum + vb3[0];
    }
}

// ---------------- launch ----------------
extern "C" void kernel_launch(void* const* d_in, const int* in_sizes, int n_in,
                              void* d_out, int out_size, void* d_ws, size_t ws_size,
                              hipStream_t stream) {
    const float* obs      = (const float*)d_in[0];
    const int*   category = (const int*)d_in[1];
    const float* v_w0 = (const float*)d_in[2];
    const float* v_b0 = (const float*)d_in[3];
    const float* v_w1 = (const float*)d_in[4];
    const float* v_b1 = (const float*)d_in[5];
    const float* v_w2 = (const float*)d_in[6];
    const float* v_b2 = (const float*)d_in[7];
    const float* v_w3 = (const float*)d_in[8];
    const float* v_b3 = (const float*)d_in[9];
    const float* q_w0 = (const float*)d_in[10];
    const float* q_b0 = (const float*)d_in[11];
    const float* q_w1 = (const float*)d_in[12];
    const float* q_b1 = (const float*)d_in[13];
    const float* q_w2 = (const float*)d_in[14];
    const float* q_b2 = (const float*)d_in[15];
    const float* q_w3 = (const float*)d_in[16];
    const float* q_b3 = (const float*)d_in[17];

    char* ws = (char*)d_ws;
    __hip_bfloat16* obs_bf = (__hip_bfloat16*)(ws + 0);              // 1 MB
    __hip_bfloat16* w1t    = (__hip_bfloat16*)(ws + 1048576);        // (512,512) tiled
    __hip_bfloat16* w2t    = (__hip_bfloat16*)(ws + 1572864);
    __hip_bfloat16* w3t    = (__hip_bfloat16*)(ws + 2097152);
    __hip_bfloat16* vw1t   = (__hip_bfloat16*)(ws + 2621440);
    __hip_bfloat16* vw2t   = (__hip_bfloat16*)(ws + 3145728);
    __hip_bfloat16* w0ta   = (__hip_bfloat16*)(ws + 3670016);        // 160 KB aug
    __hip_bfloat16* vw0ta  = (__hip_bfloat16*)(ws + 3833856);        // 160 KB aug
    __hip_bfloat16* acts_bf= (__hip_bfloat16*)(ws + 3997696);        // (131072,8) bf16, 2 MB
    float*          bias_s = (float*)         (ws + 6094848);        // 4x512 scaled fp32, 8 KB

    float* out       = (float*)d_out;
    float* out_value = out;
    float* out_adv   = out + 4096;
    float* out_nbias = out + 4096 + (size_t)B_SZ * 512;

    // 1) all prep in one dispatch (incl. aug W0 build + bias scaling + nbias)
    prep_kernel<<<10504, 256, 0, stream>>>(
        obs, category, q_w0, q_b0, q_w1, q_w2, q_w3, v_w0, v_b0, v_w1, v_w2,
        q_b1, q_b2, v_b1, v_b2,
        obs_bf, w1t, w2t, w3t, vw1t, vw2t, w0ta, vw0ta,
        acts_bf, bias_s, out_nbias);

    // 2) fused q+v MLP (2048 q-blocks + 64 v-blocks), 512 threads
    fused_kernel<<<2112, 512, 0, stream>>>(
        obs_bf, acts_bf, w0ta, vw0ta,
        w1t, bias_s, w2t, bias_s + 512, w3t, q_b3, out_adv,
        vw1t, bias_s + 1024, vw2t, bias_s + 1536, v_w3, v_b3, out_value);
}

// Round 12
// 252.516 us; speedup vs baseline: 1.0117x; 1.0117x over previous
//
#include <hip/hip_runtime.h>
#include <hip/hip_bf16.h>

// Problem constants
#define B_SZ   4096
#define OBS_N  128
#define HID    512
// tanh(x) = 1 - 2/(2^(x*2log2e)+1). We pre-scale all tanh-feeding weights and
// biases by TANH_SCALE at prep time so the fused epilogue needs no per-element
// v_mul, and the bias is folded into the MFMA accumulator init (no v_add).
#define TANH_SCALE 2.885390081777927f   // 2*log2(e)

// R22: best-of-both merge. R8's fused (152.9us: P precomputed once, phase0
// acc-init from fragment-tiled fp32 P — NOT the 32x-redundant in-fused W0
// GEMM of R19-21) + 2 dispatches (R9 proved the 3rd dispatch costs ~12us).
// The P-GEMM now lives INSIDE the prep dispatch as 256 SELF-CONTAINED blocks
// (no intra-dispatch ordering dependency): A-tiles = obs f32 loaded+converted
// in-regs -> ds_write; B-tiles = transposed-scatter of qw0/vw0 (L2-resident)
// -> ds_write; both reproduce gemm_dual's permuted LDS layout (write slot
// (c-(r>>1))&3 matches read slot (quad-(t>>1))&3). obs_bf/w0t branches
// deleted (nothing consumes them). gemm blocks FIRST in the grid so they
// overlap the 9480 streaming prep blocks.
// Fused: R18 layer loop (distance-2 weight prefetch + PAIRED ac loads, the
// zero-spill 128-VGPR config; distance-3 spills — R16), L3 head split
// across all 8 waves. Spill-volume lesson (R21): only critical-path spill
// costs time; don't trade prefetch distance for spill bytes.

typedef __bf16 bf16x8_t __attribute__((ext_vector_type(8)));
typedef float  f32x4_t  __attribute__((ext_vector_type(4)));

// input already scaled by TANH_SCALE (weights/bias pre-scaled at prep)
__device__ inline float fast_tanh_pre(float x) {
    float e = __builtin_amdgcn_exp2f(x);
    return fmaf(-2.f, __builtin_amdgcn_rcpf(e + 1.f), 1.f);
}

// hs element (row, col): chunk c = col/8, phys = (c&~7)|((c^(row&7))&7),
// offset row*512 + phys*8 + col%8.
__device__ inline int hs_off(int row, int col) {
    int c = col >> 3;
    int phys = (c & ~7) | ((c ^ (row & 7)) & 7);
    return row * 512 + phys * 8 + (col & 7);
}

// ---------------- combined prep + P-GEMM ----------------
// Grid layout (9736 blocks):
//   [0,256)       P-GEMM: p ([0,128)) / pv ([128,256)), self-contained
//   [256,4352)    acts_bf table
//   [4352,9472)   w1t/w2t/w3t/vw1t/vw2t MFMA tiling (5 x 1024)
//   [9472,9600)   w0aug + vw0aug (acts-part aug tables, 64 each)
//   [9600,9608)   bias_s (scaled fp32 biases)
//   [9608,9736)   nbias = 0 (float4)
__global__ __launch_bounds__(256) void prep_kernel(
    const float* __restrict__ obs, const int* __restrict__ category,
    const float* __restrict__ qw0, const float* __restrict__ qb0,
    const float* __restrict__ qw1, const float* __restrict__ qw2,
    const float* __restrict__ qw3,
    const float* __restrict__ vw0, const float* __restrict__ vb0,
    const float* __restrict__ vw1, const float* __restrict__ vw2,
    const float* __restrict__ qb1, const float* __restrict__ qb2,
    const float* __restrict__ vb1, const float* __restrict__ vb2,
    __hip_bfloat16* __restrict__ w1t, __hip_bfloat16* __restrict__ w2t,
    __hip_bfloat16* __restrict__ w3t,
    __hip_bfloat16* __restrict__ vw1t, __hip_bfloat16* __restrict__ vw2t,
    __hip_bfloat16* __restrict__ w0aug, __hip_bfloat16* __restrict__ vw0aug,
    __hip_bfloat16* __restrict__ acts_bf, float* __restrict__ bias_s,
    float* __restrict__ nbias,
    float* __restrict__ p, float* __restrict__ pv)
{
    __shared__ __hip_bfloat16 Asg[128 * 32];   // 8 KB (gemm branch only)
    __shared__ __hip_bfloat16 Bsg[128 * 32];   // 8 KB
    const int bid = blockIdx.x, tid = threadIdx.x;
    if (bid < 256) {           // ---- P-GEMM: C = obs @ (W0^T scaled), epi3 ----
        const bool isq = bid < 128;
        const int tb = bid & 127;
        const long m0 = (long)(tb >> 2) * 128;
        const int  n0 = (tb & 3) * 128;
        const float* Wsrc = isq ? qw0 : vw0;
        float* Cout = isq ? p : pv;

        const int wave = tid >> 6, lane = tid & 63;
        const int quad = lane >> 4, t = lane & 15;
        const int wr = wave >> 1, wc = wave & 1;
        const int slot = ((quad - (t >> 1)) & 3) * 8;

        f32x4_t acc[4][4] = {};
        const int r = tid >> 1;        // 0..127: As row / Bs n-row
        const int h = tid & 1;         // which chunk pair

        for (int k0 = 0; k0 < 128; k0 += 32) {
            // stage As: obs f32 -> bf16, permuted chunk slot (c-(r>>1))&3
            #pragma unroll
            for (int cc = 0; cc < 2; ++cc) {
                const int c = 2 * h + cc;
                const float* src = &obs[(m0 + r) * 128 + k0 + c * 8];
                float4 v0 = *(const float4*)(src);
                float4 v1 = *(const float4*)(src + 4);
                union { __hip_bfloat16 b[8]; uint4 u; } ob;
                ob.b[0] = __float2bfloat16(v0.x); ob.b[1] = __float2bfloat16(v0.y);
                ob.b[2] = __float2bfloat16(v0.z); ob.b[3] = __float2bfloat16(v0.w);
                ob.b[4] = __float2bfloat16(v1.x); ob.b[5] = __float2bfloat16(v1.y);
                ob.b[6] = __float2bfloat16(v1.z); ob.b[7] = __float2bfloat16(v1.w);
                *(uint4*)&Asg[r * 32 + ((c - (r >> 1)) & 3) * 8] = ob.u;
            }
            // stage Bs: transposed scatter of Wsrc (k-major), scaled
            #pragma unroll
            for (int cc = 0; cc < 2; ++cc) {
                const int c = 2 * h + cc;
                union { __hip_bfloat16 b[8]; uint4 u; } wb;
                #pragma unroll
                for (int e = 0; e < 8; ++e)
                    wb.b[e] = __float2bfloat16(
                        Wsrc[(size_t)(k0 + c * 8 + e) * 512 + n0 + r] * TANH_SCALE);
                *(uint4*)&Bsg[r * 32 + ((c - (r >> 1)) & 3) * 8] = wb.u;
            }
            __syncthreads();
            bf16x8_t af[4], bfr[4];
            #pragma unroll
            for (int i = 0; i < 4; ++i)
                af[i] = *(const bf16x8_t*)&Asg[(wr * 64 + i * 16 + t) * 32 + slot];
            #pragma unroll
            for (int j = 0; j < 4; ++j)
                bfr[j] = *(const bf16x8_t*)&Bsg[(wc * 64 + j * 16 + t) * 32 + slot];
            #pragma unroll
            for (int i = 0; i < 4; ++i)
                #pragma unroll
                for (int j = 0; j < 4; ++j)
                    acc[i][j] = __builtin_amdgcn_mfma_f32_16x16x32_bf16(af[i], bfr[j], acc[i][j], 0, 0, 0);
            __syncthreads();
        }
        // epi3: fragment-tiled fp32 store (matches fused phase0's acc init)
        #pragma unroll
        for (int i = 0; i < 4; ++i) {
            const long rbase = m0 + wr * 64 + i * 16 + quad * 4;
            #pragma unroll
            for (int j = 0; j < 4; ++j) {
                const int col = n0 + wc * 64 + j * 16 + t;
                #pragma unroll
                for (int rr = 0; rr < 4; ++rr) {
                    const long m = rbase + rr;
                    const int brow = (int)(m & 63);
                    const long idx =
                        ((((m >> 6) * 8 + (col >> 6)) * 16 + (brow >> 4) * 4 + ((col >> 4) & 3)) * 256)
                        + ((col >> 2) & 3) * 64 + (brow & 15) * 4 + (col & 3);
                    Cout[idx] = acc[i][j][rr];
                }
            }
        }
    } else if (bid < 4352) {   // acts_bf table, s-major bf16: acts_bf[(s*4096+b)*8+d]
        int t = (bid - 256) * 256 + tid;
        int d = t & 7;
        int r = t >> 3;
        int b = r & 4095, s = r >> 12;
        int U = (s >> 3) + ((d < (s & 7)) ? 1 : 0);
        float a = 0.f;
        if (U > 0) {
            float w = 0.125f, cum = 0.f;
            for (int j = 0; j < U; ++j) {
                cum += (float)category[b * 32 + j * 8 + d] * w;
                if (j == U - 1) a = -1.f + cum + 0.5f * w;
                w *= 0.0625f;
            }
        }
        acts_bf[t] = __float2bfloat16(a);
    } else if (bid < 9472) {   // (512,512) -> MFMA-tiled
        int job = (bid - 4352) >> 10;            // 0..4
        const float* srcs[5] = {qw1, qw2, qw3, vw1, vw2};
        __hip_bfloat16* dsts[5] = {w1t, w2t, w3t, vw1t, vw2t};
        // qw1/qw2/vw1/vw2 feed tanh -> pre-scale; qw3 (job 2) is the raw head
        float sc = (job == 2) ? 1.0f : TANH_SCALE;
        int idx = ((bid - 4352) & 1023) * 256 + tid;   // 0..262143
        int e    = idx & 7;
        int lane = (idx >> 3) & 63;
        int tile, kc;
        if (job == 2) {        // w3t keeps the old tile-major layout (L3 path)
            kc   = (idx >> 9) & 15;
            tile = idx >> 13;
        } else {               // kc-major: one kc's 4 j-frags contiguous (4KB)
            int jj = (idx >> 9) & 3;
            kc     = (idx >> 11) & 15;
            int g  = idx >> 15;
            tile = g * 4 + jj;
        }
        int k = kc * 32 + (lane >> 4) * 8 + e;
        int n = tile * 16 + (lane & 15);
        dsts[job][idx] = __float2bfloat16(srcs[job][k * 512 + n] * sc);
    } else if (bid < 9600) {   // w0aug + vw0aug (64 blocks each), pre-scaled
        int sub = bid - 9472;
        bool isv = sub >= 64;
        int idx = (sub & 63) * 256 + tid;   // 0..16383
        int e    = idx & 7;
        int lane = (idx >> 3) & 63;
        int tile = idx >> 9;
        int k = (lane >> 4) * 8 + e;
        int n = tile * 16 + (lane & 15);
        float v = 0.f;
        if (!isv) {
            if (k < 8) v = qw0[(128 + k) * 512 + n];
            else if (k == 8) v = qb0[n];
            w0aug[idx] = __float2bfloat16(v * TANH_SCALE);
        } else {
            if (k == 8) v = vb0[n];
            vw0aug[idx] = __float2bfloat16(v * TANH_SCALE);
        }
    } else if (bid < 9608) {   // scaled fp32 biases for layers 1/2: qb1|qb2|vb1|vb2
        int idx = (bid - 9600) * 256 + tid;    // 0..2047
        const float* srcs[4] = {qb1, qb2, vb1, vb2};
        bias_s[idx] = srcs[idx >> 9][idx & 511] * TANH_SCALE;
    } else {                   // nbias = 0, 4 elems/thread (float4)
        int i = (bid - 9608) * 1024 + tid * 4;
        float4 z = {0.f, 0.f, 0.f, 0.f};
        *(float4*)&nbias[i] = z;
    }
}

// ---------------- epilogue: tanh(acc) -> hs (XOR-swizzled) ----------------
// acc is pre-scaled by TANH_SCALE and already includes the bias (acc init).
__device__ inline void epi_store(
    __hip_bfloat16* hs, f32x4_t acc[4][4],
    int n0w, int quad, int t)
{
    #pragma unroll
    for (int j = 0; j < 4; ++j) {
        const int oc0 = n0w + j * 16 + quad * 4;     // 4 consecutive out cols
        const int cbase = oc0 >> 3;
        const int sub = (quad & 1) * 4;
        #pragma unroll
        for (int rt = 0; rt < 4; ++rt) {
            const int row = rt * 16 + t;
            union { __hip_bfloat16 b[4]; uint2 v; } o;
            o.b[0] = __float2bfloat16(fast_tanh_pre(acc[rt][j][0]));
            o.b[1] = __float2bfloat16(fast_tanh_pre(acc[rt][j][1]));
            o.b[2] = __float2bfloat16(fast_tanh_pre(acc[rt][j][2]));
            o.b[3] = __float2bfloat16(fast_tanh_pre(acc[rt][j][3]));
            const int phys = (cbase & ~7) | ((cbase ^ (row & 7)) & 7);
            *(uint2*)&hs[row * 512 + phys * 8 + sub] = o.v;
        }
    }
}

// ---------------- fused MLP layer: hs(64x512) = tanh(hs @ W^T + bias) ----------------
// Distance-2 weight prefetch (kc-pair loop, slots wA/wB) + PAIRED ac loads
// (a0/a1 -> 8 MFMAs -> a2/a3 -> 8 MFMAs) — R18-verified zero-spill config.
// Distance-3 spills (R16: WRITE 428MB) — do NOT add a third slot.
// bias_s is PRE-SCALED fp32 bias, folded into acc init (MFMA C-in).
__device__ inline void mfma_layer(
    __hip_bfloat16* hs, const __hip_bfloat16* __restrict__ Wt,
    const float* __restrict__ bias_s, int w, int lane)
{
    const int quad = lane >> 4, t = lane & 15;
    const int n0w = w * 64;
    // kc-major weight tiling: wave w's block = 32768 elems; per kc the 4
    // j-frags sit at consecutive 1KB offsets.
    const __hip_bfloat16* Wl = Wt + (size_t)w * 32768 + (size_t)lane * 8;
    f32x4_t acc[4][4];   // [rt = batch tile][j = out tile]
    #pragma unroll
    for (int j = 0; j < 4; ++j) {
        const f32x4_t bv = *(const f32x4_t*)&bias_s[n0w + j * 16 + quad * 4];
        #pragma unroll
        for (int rt = 0; rt < 4; ++rt)
            acc[rt][j] = bv;
    }
    bf16x8_t wA[4], wB[4];
    #pragma unroll
    for (int j = 0; j < 4; ++j) {
        wA[j] = *(const bf16x8_t*)(Wl + (size_t)(0 * 4 + j) * 512);
        wB[j] = *(const bf16x8_t*)(Wl + (size_t)(1 * 4 + j) * 512);
    }

    for (int m = 0; m < 8; ++m) {          // kc = 2m (slot A), 2m+1 (slot B)
        {   // even kc
            const int kc = 2 * m;
            const int craw = kc * 4 + quad;
            const int phys = (craw & ~7) | ((craw ^ (t & 7)) & 7);
            const __hip_bfloat16* hrow = &hs[t * 512 + phys * 8];
            bf16x8_t a0 = *(const bf16x8_t*)(hrow);
            bf16x8_t a1 = *(const bf16x8_t*)(hrow + 8192);
            __builtin_amdgcn_s_setprio(1);
            #pragma unroll
            for (int j = 0; j < 4; ++j) {
                acc[0][j] = __builtin_amdgcn_mfma_f32_16x16x32_bf16(wA[j], a0, acc[0][j], 0, 0, 0);
                acc[1][j] = __builtin_amdgcn_mfma_f32_16x16x32_bf16(wA[j], a1, acc[1][j], 0, 0, 0);
            }
            bf16x8_t a2 = *(const bf16x8_t*)(hrow + 2 * 8192);
            bf16x8_t a3 = *(const bf16x8_t*)(hrow + 3 * 8192);
            #pragma unroll
            for (int j = 0; j < 4; ++j) {
                acc[2][j] = __builtin_amdgcn_mfma_f32_16x16x32_bf16(wA[j], a2, acc[2][j], 0, 0, 0);
                acc[3][j] = __builtin_amdgcn_mfma_f32_16x16x32_bf16(wA[j], a3, acc[3][j], 0, 0, 0);
            }
            __builtin_amdgcn_s_setprio(0);
            if (m < 7) {
                #pragma unroll
                for (int j = 0; j < 4; ++j)
                    wA[j] = *(const bf16x8_t*)(Wl + (size_t)((kc + 2) * 4 + j) * 512);
            }
        }
        {   // odd kc
            const int kc = 2 * m + 1;
            const int craw = kc * 4 + quad;
            const int phys = (craw & ~7) | ((craw ^ (t & 7)) & 7);
            const __hip_bfloat16* hrow = &hs[t * 512 + phys * 8];
            bf16x8_t a0 = *(const bf16x8_t*)(hrow);
            bf16x8_t a1 = *(const bf16x8_t*)(hrow + 8192);
            __builtin_amdgcn_s_setprio(1);
            #pragma unroll
            for (int j = 0; j < 4; ++j) {
                acc[0][j] = __builtin_amdgcn_mfma_f32_16x16x32_bf16(wB[j], a0, acc[0][j], 0, 0, 0);
                acc[1][j] = __builtin_amdgcn_mfma_f32_16x16x32_bf16(wB[j], a1, acc[1][j], 0, 0, 0);
            }
            bf16x8_t a2 = *(const bf16x8_t*)(hrow + 2 * 8192);
            bf16x8_t a3 = *(const bf16x8_t*)(hrow + 3 * 8192);
            #pragma unroll
            for (int j = 0; j < 4; ++j) {
                acc[2][j] = __builtin_amdgcn_mfma_f32_16x16x32_bf16(wB[j], a2, acc[2][j], 0, 0, 0);
                acc[3][j] = __builtin_amdgcn_mfma_f32_16x16x32_bf16(wB[j], a3, acc[3][j], 0, 0, 0);
            }
            __builtin_amdgcn_s_setprio(0);
            if (m < 7) {
                #pragma unroll
                for (int j = 0; j < 4; ++j)
                    wB[j] = *(const bf16x8_t*)(Wl + (size_t)((kc + 2) * 4 + j) * 512);
            }
        }
    }
    __syncthreads();   // all reads of hs complete
    epi_store(hs, acc, n0w, quad, t);
    __syncthreads();   // hs now holds the layer output
}

// ---------------- fused MLP kernel: q-blocks [0,2048), v-blocks [2048,2112) ----------------
__global__ __launch_bounds__(512, 4) void fused_kernel(
    const float* __restrict__ p,               // fragment-tiled fp32 = obs@W0 (pre-scaled)
    const float* __restrict__ pv,              // fragment-tiled fp32 = obs@vW0 (pre-scaled)
    const __hip_bfloat16* __restrict__ acts_bf,// (131072,8) bf16 s-major
    const __hip_bfloat16* __restrict__ w0aug,  // tiled aug (32 tiles), pre-scaled
    const __hip_bfloat16* __restrict__ vw0aug,
    const __hip_bfloat16* __restrict__ w1t, const float* __restrict__ qb1s,
    const __hip_bfloat16* __restrict__ w2t, const float* __restrict__ qb2s,
    const __hip_bfloat16* __restrict__ w3t, const float* __restrict__ qb3,
    float* __restrict__ advout,
    const __hip_bfloat16* __restrict__ vw1t, const float* __restrict__ vb1s,
    const __hip_bfloat16* __restrict__ vw2t, const float* __restrict__ vb2s,
    const float* __restrict__ vw3, const float* __restrict__ vb3,
    float* __restrict__ vout)
{
    __shared__ __hip_bfloat16 hs[64 * 512];   // 64 KB
    const int bid = blockIdx.x;
    const int tid = threadIdx.x;
    const int w = tid >> 6, lane = tid & 63;
    const int quad = lane >> 4, t = lane & 15;
    const bool is_q = bid < 2048;
    const int s  = is_q ? (bid >> 6) : 0;
    const int mb = is_q ? (bid & 63) : (bid - 2048);
    const int n0w = w * 64;

    // ---- phase 0 as MFMA: D = W0aug·[acts;1] + p (acc init from tiled fp32 P) ----
    {
        const float* Pt = (is_q ? p : pv) + (((size_t)mb * 8 + w) * 16) * 256 + lane * 4;
        const __hip_bfloat16* W0 = is_q ? w0aug : vw0aug;
        f32x4_t acc[4][4];
        #pragma unroll
        for (int rt = 0; rt < 4; ++rt)
            #pragma unroll
            for (int j = 0; j < 4; ++j)
                acc[rt][j] = *(const f32x4_t*)(Pt + (rt * 4 + j) * 256);
        // B-frags: quad0 = acts (q only), quad1 = e0 1.0, else 0
        bf16x8_t bfrag[4];
        #pragma unroll
        for (int rt = 0; rt < 4; ++rt) {
            union { bf16x8_t vec; unsigned short u[8]; } bu;
            #pragma unroll
            for (int i = 0; i < 8; ++i) bu.u[i] = 0;
            if (quad == 1) bu.u[0] = 0x3F80;   // bf16 1.0
            if (is_q && quad == 0) {
                const long r = (long)s * 4096 + mb * 64 + rt * 16 + t;
                bu.vec = *(const bf16x8_t*)&acts_bf[r * 8];
            }
            bfrag[rt] = bu.vec;
        }
        bf16x8_t wq[4];
        #pragma unroll
        for (int j = 0; j < 4; ++j)
            wq[j] = *(const bf16x8_t*)(W0 + ((size_t)(w * 4 + j) * 64 + lane) * 8);
        __builtin_amdgcn_s_setprio(1);
        #pragma unroll
        for (int j = 0; j < 4; ++j)
            #pragma unroll
            for (int rt = 0; rt < 4; ++rt)
                acc[rt][j] = __builtin_amdgcn_mfma_f32_16x16x32_bf16(wq[j], bfrag[rt], acc[rt][j], 0, 0, 0);
        __builtin_amdgcn_s_setprio(0);
        epi_store(hs, acc, n0w, quad, t);
    }
    __syncthreads();

    // ---- layers 1 and 2 ----
    mfma_layer(hs, is_q ? w1t : vw1t, is_q ? qb1s : vb1s, w, lane);
    mfma_layer(hs, is_q ? w2t : vw2t, is_q ? qb2s : vb2s, w, lane);

    // ---- layer 3 ----
    if (is_q) {
        // diag slice: 64 rows x 16 cols. ALL 8 waves: w&3 picks the row group,
        // w>>2 picks the kc half (0-7 / 8-15); partials in two LDS slabs.
        f32x4_t acc = {};
        {
            const __hip_bfloat16* W3l = w3t + ((size_t)s * 16 * 64 + (size_t)lane) * 8;
            const int kc0 = (w >> 2) * 8;
            const int wrow = (w & 3) * 16 + t;
            #pragma unroll
            for (int kk = 0; kk < 8; ++kk) {
                const int kc = kc0 + kk;
                const int craw = kc * 4 + quad;
                const int phys = (craw & ~7) | ((craw ^ (t & 7)) & 7);
                bf16x8_t a = *(const bf16x8_t*)&hs[wrow * 512 + phys * 8];
                bf16x8_t bq = *(const bf16x8_t*)(W3l + (size_t)kc * 512);
                acc = __builtin_amdgcn_mfma_f32_16x16x32_bf16(a, bq, acc, 0, 0, 0);
            }
        }
        __syncthreads();   // L3 reads of hs done; hs reusable as fp32 staging
        float* hsf = (float*)hs;   // two 64x16 fp32 slabs: [0..1023] and [1024..2047]
        {
            const float add = (w < 4) ? qb3[s * 16 + t] : 0.f;   // bias once
            const int base = (w >> 2) * 1024;
            #pragma unroll
            for (int rr = 0; rr < 4; ++rr)
                hsf[base + ((w & 3) * 16 + quad * 4 + rr) * 16 + t] = acc[rr] + add;
        }
        __syncthreads();
        // coalesced store: thread -> (row = tid>>3, colpair = tid&7), 64B/row
        const int row = tid >> 3, cp = tid & 7;
        float2 lo = *(const float2*)&hsf[row * 16 + cp * 2];
        float2 hi = *(const float2*)&hsf[1024 + row * 16 + cp * 2];
        float2 v2 = {lo.x + hi.x, lo.y + hi.y};
        *(float2*)&advout[(size_t)(mb * 64 + row) * 512 + s * 16 + cp * 2] = v2;
    } else {
        // value head: row = tid>>3 (0..63), seg = tid&7 sums 64 elems
        const int row = tid >> 3, seg = tid & 7;
        float sum = 0.f;
        for (int k = seg * 64; k < seg * 64 + 64; ++k)
            sum += __bfloat162float(hs[hs_off(row, k)]) * vw3[k];
        sum += __shfl_xor(sum, 1);
        sum += __shfl_xor(sum, 2);
        sum += __shfl_xor(sum, 4);
        if (seg == 0) vout[mb * 64 + row] = sum + vb3[0];
    }
}

// ---------------- launch ----------------
extern "C" void kernel_launch(void* const* d_in, const int* in_sizes, int n_in,
                              void* d_out, int out_size, void* d_ws, size_t ws_size,
                              hipStream_t stream) {
    const float* obs      = (const float*)d_in[0];
    const int*   category = (const int*)d_in[1];
    const float* v_w0 = (const float*)d_in[2];
    const float* v_b0 = (const float*)d_in[3];
    const float* v_w1 = (const float*)d_in[4];
    const float* v_b1 = (const float*)d_in[5];
    const float* v_w2 = (const float*)d_in[6];
    const float* v_b2 = (const float*)d_in[7];
    const float* v_w3 = (const float*)d_in[8];
    const float* v_b3 = (const float*)d_in[9];
    const float* q_w0 = (const float*)d_in[10];
    const float* q_b0 = (const float*)d_in[11];
    const float* q_w1 = (const float*)d_in[12];
    const float* q_b1 = (const float*)d_in[13];
    const float* q_w2 = (const float*)d_in[14];
    const float* q_b2 = (const float*)d_in[15];
    const float* q_w3 = (const float*)d_in[16];
    const float* q_b3 = (const float*)d_in[17];

    char* ws = (char*)d_ws;
    __hip_bfloat16* w1t    = (__hip_bfloat16*)(ws + 0);              // (512,512) tiled
    __hip_bfloat16* w2t    = (__hip_bfloat16*)(ws + 524288);
    __hip_bfloat16* w3t    = (__hip_bfloat16*)(ws + 1048576);
    __hip_bfloat16* vw1t   = (__hip_bfloat16*)(ws + 1572864);
    __hip_bfloat16* vw2t   = (__hip_bfloat16*)(ws + 2097152);
    __hip_bfloat16* w0aug  = (__hip_bfloat16*)(ws + 2621440);        // 32 KB
    __hip_bfloat16* vw0aug = (__hip_bfloat16*)(ws + 2654208);        // 32 KB
    __hip_bfloat16* acts_bf= (__hip_bfloat16*)(ws + 2686976);        // (131072,8) bf16, 2 MB
    float*          bias_s = (float*)         (ws + 4784128);        // 4x512 scaled fp32, 8 KB
    float*          p      = (float*)         (ws + 4792320);        // tiled fp32, 8 MB
    float*          pv     = (float*)         (ws + 13180928);       // tiled fp32, 8 MB

    float* out       = (float*)d_out;
    float* out_value = out;
    float* out_adv   = out + 4096;
    float* out_nbias = out + 4096 + (size_t)B_SZ * 512;

    // 1) prep + P-GEMM in ONE dispatch (gemm blocks first, self-contained)
    prep_kernel<<<9736, 256, 0, stream>>>(
        obs, category, q_w0, q_b0, q_w1, q_w2, q_w3, v_w0, v_b0, v_w1, v_w2,
        q_b1, q_b2, v_b1, v_b2,
        w1t, w2t, w3t, vw1t, vw2t, w0aug, vw0aug,
        acts_bf, bias_s, out_nbias, p, pv);

    // 2) fused q+v MLP (2048 q-blocks + 64 v-blocks), 512 threads
    fused_kernel<<<2112, 512, 0, stream>>>(
        p, pv, acts_bf, w0aug, vw0aug,
        w1t, bias_s, w2t, bias_s + 512, w3t, q_b3, out_adv,
        vw1t, bias_s + 1024, vw2t, bias_s + 1536, v_w3, v_b3, out_value);
}